// Round 14
// baseline (831.648 us; speedup 1.0000x reference)
//
#include <hip/hip_runtime.h>
#include <hip/hip_bf16.h>
#include <cstddef>

// Problem constants
#define BB    256
#define TT    512
#define DIN   64
#define H1    256
#define INTER 128
#define STATE 256
#define MOTOR 64
#define DOUT  32
#define BT    (BB*TT)   // 131072

typedef unsigned int u32;
typedef short short8 __attribute__((ext_vector_type(8)));
typedef float f32x4  __attribute__((ext_vector_type(4)));
typedef float f32x2  __attribute__((ext_vector_type(2)));

// Packed-weight (hi/lo bf16 in one u32) fragment-order offsets, in u32 elems
#define OFF_I1 0         // Wi1: 64x256   -> 16384
#define OFF_I2 16384     // Wi2: 256x256  -> 65536
#define OFF_I3 81920     // Wi3: 256x128  -> 32768
#define OFF_IH 114688    // Wih: 128x256  -> 32768
#define OFF_O1 147456    // Wo1: 64x256   -> 16384
#define OFF_O2 163840    // Wo2: 256x256  -> 65536
#define OFF_O3 229376    // Wo3: 256x32   -> 8192
#define BPK_TOTAL 237568

__device__ __forceinline__ float tanh_fast(float x) {
    float e = __expf(2.0f * x);
    return 1.0f - 2.0f / (e + 1.0f);
}

__device__ __forceinline__ u32 f2u(float f){ union{float f; u32 u;} v; v.f=f; return v.u; }
__device__ __forceinline__ float u2f(u32 u){ union{u32 u; float f;} v; v.u=u; return v.f; }

// fp32 -> packed (hi bf16 in [15:0], residual-lo bf16 in [31:16]), RNE both.
__device__ __forceinline__ u32 packhl(float x) {
    u32 b  = f2u(x);
    u32 hi = (b + 0x7fffu + ((b >> 16) & 1u)) >> 16;
    float lo = x - u2f(hi << 16);
    u32 bl = f2u(lo);
    u32 l16 = (bl + 0x7fffu + ((bl >> 16) & 1u)) >> 16;
    return (hi & 0xffffu) | (l16 << 16);
}

// 8 packed u32 -> hi-frag / lo-frag (each 8 bf16 as short8)
__device__ __forceinline__ void unpack8(uint4 w0, uint4 w1, short8& hi, short8& lo) {
    union { u32 u[4]; short8 s; } H, L;
    H.u[0] = __builtin_amdgcn_perm(w0.y, w0.x, 0x05040100u);
    L.u[0] = __builtin_amdgcn_perm(w0.y, w0.x, 0x07060302u);
    H.u[1] = __builtin_amdgcn_perm(w0.w, w0.z, 0x05040100u);
    L.u[1] = __builtin_amdgcn_perm(w0.w, w0.z, 0x07060302u);
    H.u[2] = __builtin_amdgcn_perm(w1.y, w1.x, 0x05040100u);
    L.u[2] = __builtin_amdgcn_perm(w1.y, w1.x, 0x07060302u);
    H.u[3] = __builtin_amdgcn_perm(w1.w, w1.z, 0x05040100u);
    L.u[3] = __builtin_amdgcn_perm(w1.w, w1.z, 0x07060302u);
    hi = H.s; lo = L.s;
}

// LDS activation addressing: [64 rows][256 words], XOR-swizzled in 16B units.
__device__ __forceinline__ int swz(int row, int col) {
    return row * 256 + (col ^ ((row & 7) << 2));
}

// ---------------------------------------------------------------------------
// One MFMA MLP layer over a 64-token tile held in LDS (packed hi/lo u32).
//   Split-bf16: D += Ahi*Bhi + Ahi*Blo + Alo*Bhi  (~fp32 accuracy).
// ---------------------------------------------------------------------------
template<int K, int N, bool TANH, bool TOGLOBAL>
__device__ __forceinline__ void mfma_layer(
    const u32* __restrict__ Bpk, const float* __restrict__ bias,
    const u32* inB, u32* outB, float* __restrict__ gout,
    int lane, int wv)
{
    constexpr int NF  = N / 16;
    constexpr int NFW = (NF >= 4) ? NF / 4 : 1;
    constexpr int KC  = K / 32;
    const int q = lane >> 4, c = lane & 15;
    const int nf0 = wv * NFW;
    if (nf0 >= NF) return;   // small-N layers idle the upper waves

    f32x4 acc[4][NFW];
    #pragma unroll
    for (int nf = 0; nf < NFW; ++nf) {
        float bv = bias[(nf0 + nf) * 16 + c];
        #pragma unroll
        for (int rf = 0; rf < 4; ++rf) acc[rf][nf] = (f32x4){bv, bv, bv, bv};
    }

    #pragma unroll 2
    for (int kc = 0; kc < KC; ++kc) {
        short8 ahi[4], alo[4];
        #pragma unroll
        for (int rf = 0; rf < 4; ++rf) {
            int row = rf * 16 + c;
            int kb  = kc * 32 + q * 8;
            int m4  = (row & 7) << 2;
            uint4 w0 = *(const uint4*)(inB + row * 256 + ( kb      ^ m4));
            uint4 w1 = *(const uint4*)(inB + row * 256 + ((kb + 4) ^ m4));
            unpack8(w0, w1, ahi[rf], alo[rf]);
        }
        #pragma unroll
        for (int nf = 0; nf < NFW; ++nf) {
            const u32* bp = Bpk + (((size_t)(kc * NF + nf0 + nf) * 64 + lane) * 8);
            uint4 b0 = *(const uint4*)bp;
            uint4 b1 = *(const uint4*)(bp + 4);
            short8 bhi, blo; unpack8(b0, b1, bhi, blo);
            #pragma unroll
            for (int rf = 0; rf < 4; ++rf) {
                acc[rf][nf] = __builtin_amdgcn_mfma_f32_16x16x32_bf16(ahi[rf], bhi, acc[rf][nf], 0, 0, 0);
                acc[rf][nf] = __builtin_amdgcn_mfma_f32_16x16x32_bf16(ahi[rf], blo, acc[rf][nf], 0, 0, 0);
                acc[rf][nf] = __builtin_amdgcn_mfma_f32_16x16x32_bf16(alo[rf], bhi, acc[rf][nf], 0, 0, 0);
            }
        }
    }

    #pragma unroll
    for (int rf = 0; rf < 4; ++rf) {
        #pragma unroll
        for (int nf = 0; nf < NFW; ++nf) {
            #pragma unroll
            for (int r = 0; r < 4; ++r) {
                float v = acc[rf][nf][r];
                if (TANH) v = tanh_fast(v);
                int row = rf * 16 + q * 4 + r;
                int col = (nf0 + nf) * 16 + c;
                if (TOGLOBAL) gout[(size_t)row * N + col] = v;
                else          outB[swz(row, col)] = packhl(v);
            }
        }
    }
}

// Stage a [64 tokens][64 cols] fp32 global tile into packed LDS (cols 0..63).
__device__ __forceinline__ void stage64(const float* __restrict__ src, u32* dst, int tid) {
    int tt = tid >> 4;
    int c4 = (tid & 15) * 4;
    #pragma unroll
    for (int i = 0; i < 4; ++i) {
        int tok = tt + 16 * i;
        float4 v = *(const float4*)(src + (size_t)tok * 64 + c4);
        uint4 p;
        p.x = packhl(v.x); p.y = packhl(v.y); p.z = packhl(v.z); p.w = packhl(v.w);
        *(uint4*)(dst + swz(tok, c4)) = p;
    }
}

// ---------------------------------------------------------------------------
// prep: pack all MLP weights into MFMA-fragment order (hi/lo u32), and build
// WpT = [Whh^T (256 rows) ; Who^T (64 rows)], each row 256 floats.
// ---------------------------------------------------------------------------
__global__ __launch_bounds__(256) void prep_kernel(
    const float* __restrict__ Wi1, const float* __restrict__ Wi2,
    const float* __restrict__ Wi3, const float* __restrict__ Wih,
    const float* __restrict__ Wo1, const float* __restrict__ Wo2,
    const float* __restrict__ Wo3,
    const float* __restrict__ Whh, const float* __restrict__ Who,
    u32* __restrict__ Bpk, float* __restrict__ WpT)
{
    int idx = blockIdx.x * 256 + threadIdx.x;
    if (idx < BPK_TOTAL) {
        const float* W; int NF; int i = idx;
        if      (i < OFF_I2) { W = Wi1; NF = 16; i -= OFF_I1; }
        else if (i < OFF_I3) { W = Wi2; NF = 16; i -= OFF_I2; }
        else if (i < OFF_IH) { W = Wi3; NF = 8;  i -= OFF_I3; }
        else if (i < OFF_O1) { W = Wih; NF = 16; i -= OFF_IH; }
        else if (i < OFF_O2) { W = Wo1; NF = 16; i -= OFF_O1; }
        else if (i < OFF_O3) { W = Wo2; NF = 16; i -= OFF_O2; }
        else                 { W = Wo3; NF = 2;  i -= OFF_O3; }
        int e = i & 7, l = (i >> 3) & 63, t = i >> 9;
        int nf = t % NF, kc = t / NF;
        int k = kc * 32 + ((l >> 4) * 8) + e;
        int n = nf * 16 + (l & 15);
        Bpk[idx] = packhl(W[(size_t)k * (NF * 16) + n]);
    } else if (idx < BPK_TOTAL + STATE*STATE) {
        int i = idx - BPK_TOTAL; int j = i >> 8, n = i & 255;
        WpT[n * STATE + j] = Whh[j * STATE + n];
    } else if (idx < BPK_TOTAL + STATE*STATE + STATE*MOTOR) {
        int i = idx - BPK_TOTAL - STATE*STATE; int j = i >> 6, o = i & 63;
        WpT[(size_t)(STATE + o) * STATE + j] = Who[j * MOTOR + o];
    }
}

// ---------------------------------------------------------------------------
// MFMA encoder: x -> tanh(Wi1) -> tanh(Wi2) -> Wi3 -> (Wih + bh) = u
// ---------------------------------------------------------------------------
__global__ __launch_bounds__(256, 1) void encoder_mfma(
    const float* __restrict__ x, const u32* __restrict__ Bpk,
    const float* __restrict__ bi1, const float* __restrict__ bi2,
    const float* __restrict__ bi3, const float* __restrict__ bh,
    float* __restrict__ u)
{
    __shared__ u32 buf0[64 * 256];
    __shared__ u32 buf1[64 * 256];
    const int tid = threadIdx.x, lane = tid & 63, wv = tid >> 6;
    const size_t row0 = (size_t)blockIdx.x * 64;

    stage64(x + row0 * DIN, buf0, tid);
    __syncthreads();
    mfma_layer<DIN,  H1,    true,  false>(Bpk + OFF_I1, bi1, buf0, buf1, nullptr, lane, wv);
    __syncthreads();
    mfma_layer<H1,   H1,    true,  false>(Bpk + OFF_I2, bi2, buf1, buf0, nullptr, lane, wv);
    __syncthreads();
    mfma_layer<H1,   INTER, false, false>(Bpk + OFF_I3, bi3, buf0, buf1, nullptr, lane, wv);
    __syncthreads();
    mfma_layer<INTER,STATE, false, true >(Bpk + OFF_IH, bh,  buf1, nullptr, u + row0 * STATE, lane, wv);
}

// ---------------------------------------------------------------------------
// MFMA decoder: m -> tanh(Wo1) -> tanh(Wo2) -> Wo3 -> y
// ---------------------------------------------------------------------------
__global__ __launch_bounds__(256, 1) void decoder_mfma(
    const float* __restrict__ m, const u32* __restrict__ Bpk,
    const float* __restrict__ bo1, const float* __restrict__ bo2,
    const float* __restrict__ bo3,
    float* __restrict__ y)
{
    __shared__ u32 buf0[64 * 256];
    __shared__ u32 buf1[64 * 256];
    const int tid = threadIdx.x, lane = tid & 63, wv = tid >> 6;
    const size_t row0 = (size_t)blockIdx.x * 64;

    stage64(m + row0 * MOTOR, buf0, tid);
    __syncthreads();
    mfma_layer<MOTOR, H1,   true,  false>(Bpk + OFF_O1, bo1, buf0, buf1, nullptr, lane, wv);
    __syncthreads();
    mfma_layer<H1,    H1,   true,  false>(Bpk + OFF_O2, bo2, buf1, buf0, nullptr, lane, wv);
    __syncthreads();
    mfma_layer<H1,    DOUT, false, true >(Bpk + OFF_O3, bo3, buf0, nullptr, y + row0 * DOUT, lane, wv);
}

// ---------------------------------------------------------------------------
// RNN scan v14: 16-lane groups — HALVE the post-barrier DS-read burst.
// 256 blocks x 1 sample, 512 threads (8 waves, 2/SIMD), 1 barrier/step.
//
// Evidence (v11->v13): VALU halved -> flat; LDS exchange deleted -> flat;
// conflicts zeroed -> flat. Time pinned ~2200cyc/step => the barrier locksteps
// all 8 waves, so each step opens with 64 ds_read_b128 slamming the DS pipe
// (~768cyc drain ON the critical path), then the dependent tail + barrier.
// Fix: 32 groups x 16 lanes; thread covers a 16-float k-slice (4 b128 reads,
// burst 64 -> 32 insts) and owns 10 outputs (8 Whh rows + 2 Who rows).
// DPP-16 butterfly (4 stages: xor1, xor2, half_mirror, row_mirror — first 3
// verified in v13) replaces any LDS exchange. Weights 160 floats (invariant
// at 512 threads). Rotation r=((s>>1)+ii)&3: the 16 lanes' 4-bank windows
// tile all 32 banks at exactly 2-way (free, m136).
// ---------------------------------------------------------------------------
__device__ __forceinline__ float dpp_reduce16(float v) {
    int x;
    x = __float_as_int(v);
    v += __int_as_float(__builtin_amdgcn_update_dpp(0, x, 0xB1, 0xF, 0xF, true));   // quad_perm(1,0,3,2)
    x = __float_as_int(v);
    v += __int_as_float(__builtin_amdgcn_update_dpp(0, x, 0x4E, 0xF, 0xF, true));   // quad_perm(2,3,0,1)
    x = __float_as_int(v);
    v += __int_as_float(__builtin_amdgcn_update_dpp(0, x, 0x141, 0xF, 0xF, true));  // row_half_mirror
    x = __float_as_int(v);
    v += __int_as_float(__builtin_amdgcn_update_dpp(0, x, 0x140, 0xF, 0xF, true));  // row_mirror (16)
    return v;
}

__global__ __launch_bounds__(512, 2) void rnn_kernel(
    const float* __restrict__ u,      // [B*T, STATE]
    const float* __restrict__ WpT,    // [320][256] = [WhhT ; WhoT]
    const float* __restrict__ bo,     // [MOTOR]
    float* __restrict__ m)            // [B*T, MOTOR]
{
    __shared__ float hb[2][STATE];

    const int tid   = threadIdx.x;
    const int b     = blockIdx.x;
    const int s     = tid & 15;          // k-slice: [16s, 16s+16)
    const int g     = tid >> 4;          // 0..31
    const int kbase = s * 16;

    // --- weights -> registers as f32x2 pairs (uniform shape/order) ---
    // o=0..7: Whh rows 8g+o ; o=8,9: Who rows 2g+(o-8). 160 floats.
    f32x2 wp[10][8];
    #pragma unroll
    for (int o = 0; o < 10; ++o) {
        const int row = (o < 8) ? (8 * g + o) : (STATE + 2 * g + (o - 8));
        const float* wr = WpT + (size_t)row * STATE + kbase;
        #pragma unroll
        for (int ii = 0; ii < 4; ++ii) {
            int rot = ((s >> 1) + ii) & 3;
            f32x4 w = *(const f32x4*)(wr + 4 * rot);
            wp[o][2*ii]   = __builtin_shufflevector(w, w, 0, 1);
            wp[o][2*ii+1] = __builtin_shufflevector(w, w, 2, 3);
        }
    }

    // --- precomputed rotated h-read pointers (both buffers) ---
    const f32x4* hp0[4];
    const f32x4* hp1[4];
    #pragma unroll
    for (int ii = 0; ii < 4; ++ii) {
        int off = kbase + 4 * (((s >> 1) + ii) & 3);
        hp0[ii] = (const f32x4*)(hb[0] + off);
        hp1[ii] = (const f32x4*)(hb[1] + off);
    }

    const bool ish  = (s < 8);           // publishes h-row hidx
    const bool ism  = (s == 8) || (s == 9);  // stores m-row mcol
    const int  hidx = 8 * g + (s & 7);
    const int  mcol = 2 * g + (s & 1);   // valid for s==8 (->2g), s==9 (->2g+1)

    const float bov  = ism ? bo[mcol] : 0.f;
    const float* ubase = u + (size_t)b * TT * STATE + hidx;   // ish lanes
    float*       mst   = m + (size_t)b * TT * MOTOR + mcol;   // ism cursor

    if (tid < STATE) hb[0][tid] = 0.f;
    float up = ish ? ubase[0] : 0.f;   // u_0
    __syncthreads();

    // body: read h_{t-1} via HP (compile-time buffer), publish h_t to HWR.
#define RNN_BODY(T, HP, HWR)                                                   \
    {                                                                          \
        float upn = 0.f;                                                       \
        if (ish && (T) + 1 < TT) upn = ubase[(size_t)((T) + 1) * STATE];       \
        f32x2 A0 = {0.f,0.f}, A1 = {0.f,0.f}, A2 = {0.f,0.f}, A3 = {0.f,0.f};  \
        f32x2 A4 = {0.f,0.f}, A5 = {0.f,0.f}, A6 = {0.f,0.f}, A7 = {0.f,0.f};  \
        f32x2 A8 = {0.f,0.f}, A9 = {0.f,0.f};                                  \
        _Pragma("unroll")                                                      \
        for (int ii = 0; ii < 4; ++ii) {                                       \
            f32x4 hv = *HP[ii];                                                \
            f32x2 hA = __builtin_shufflevector(hv, hv, 0, 1);                  \
            f32x2 hB = __builtin_shufflevector(hv, hv, 2, 3);                  \
            A0 = __builtin_elementwise_fma(wp[0][2*ii],   hA, A0);             \
            A0 = __builtin_elementwise_fma(wp[0][2*ii+1], hB, A0);             \
            A1 = __builtin_elementwise_fma(wp[1][2*ii],   hA, A1);             \
            A1 = __builtin_elementwise_fma(wp[1][2*ii+1], hB, A1);             \
            A2 = __builtin_elementwise_fma(wp[2][2*ii],   hA, A2);             \
            A2 = __builtin_elementwise_fma(wp[2][2*ii+1], hB, A2);             \
            A3 = __builtin_elementwise_fma(wp[3][2*ii],   hA, A3);             \
            A3 = __builtin_elementwise_fma(wp[3][2*ii+1], hB, A3);             \
            A4 = __builtin_elementwise_fma(wp[4][2*ii],   hA, A4);             \
            A4 = __builtin_elementwise_fma(wp[4][2*ii+1], hB, A4);             \
            A5 = __builtin_elementwise_fma(wp[5][2*ii],   hA, A5);             \
            A5 = __builtin_elementwise_fma(wp[5][2*ii+1], hB, A5);             \
            A6 = __builtin_elementwise_fma(wp[6][2*ii],   hA, A6);             \
            A6 = __builtin_elementwise_fma(wp[6][2*ii+1], hB, A6);             \
            A7 = __builtin_elementwise_fma(wp[7][2*ii],   hA, A7);             \
            A7 = __builtin_elementwise_fma(wp[7][2*ii+1], hB, A7);             \
            A8 = __builtin_elementwise_fma(wp[8][2*ii],   hA, A8);             \
            A8 = __builtin_elementwise_fma(wp[8][2*ii+1], hB, A8);             \
            A9 = __builtin_elementwise_fma(wp[9][2*ii],   hA, A9);             \
            A9 = __builtin_elementwise_fma(wp[9][2*ii+1], hB, A9);             \
        }                                                                      \
        float r0 = dpp_reduce16(A0.x + A0.y);                                  \
        float r1 = dpp_reduce16(A1.x + A1.y);                                  \
        float r2 = dpp_reduce16(A2.x + A2.y);                                  \
        float r3 = dpp_reduce16(A3.x + A3.y);                                  \
        float r4 = dpp_reduce16(A4.x + A4.y);                                  \
        float r5 = dpp_reduce16(A5.x + A5.y);                                  \
        float r6 = dpp_reduce16(A6.x + A6.y);                                  \
        float r7 = dpp_reduce16(A7.x + A7.y);                                  \
        float r8 = dpp_reduce16(A8.x + A8.y);                                  \
        float r9 = dpp_reduce16(A9.x + A9.y);                                  \
        float v = (s == 0) ? r0 : (s == 1) ? r1 : (s == 2) ? r2 : (s == 3) ? r3\
                : (s == 4) ? r4 : (s == 5) ? r5 : (s == 6) ? r6 : (s == 7) ? r7\
                : (s == 8) ? r8 : r9;                                          \
        if (ish) {                                                             \
            if ((T) < TT) HWR[hidx] = tanh_fast(v + up);                       \
        } else if (ism && (T) > 0) {                                           \
            mst[0] = v + bov;                                                  \
            mst += MOTOR;                                                      \
        }                                                                      \
        __syncthreads();                                                       \
        up = upn;                                                              \
    }

    for (int t = 0; t <= TT; t += 2) {
        RNN_BODY(t,     hp0, (hb[1]));      // even t: read hb0, write hb1
        if (t + 1 <= TT)
            RNN_BODY(t + 1, hp1, (hb[0]));  // odd t: read hb1, write hb0
    }
#undef RNN_BODY
}

// ---------------------------------------------------------------------------
extern "C" void kernel_launch(void* const* d_in, const int* in_sizes, int n_in,
                              void* d_out, int out_size, void* d_ws, size_t ws_size,
                              hipStream_t stream) {
    const float* x   = (const float*)d_in[0];
    const float* Wi1 = (const float*)d_in[1];
    const float* bi1 = (const float*)d_in[2];
    const float* Wi2 = (const float*)d_in[3];
    const float* bi2 = (const float*)d_in[4];
    const float* Wi3 = (const float*)d_in[5];
    const float* bi3 = (const float*)d_in[6];
    const float* Wih = (const float*)d_in[7];
    const float* Whh = (const float*)d_in[8];
    const float* bh  = (const float*)d_in[9];
    const float* Who = (const float*)d_in[10];
    const float* bo  = (const float*)d_in[11];
    const float* Wo1 = (const float*)d_in[12];
    const float* bo1 = (const float*)d_in[13];
    const float* Wo2 = (const float*)d_in[14];
    const float* bo2 = (const float*)d_in[15];
    const float* Wo3 = (const float*)d_in[16];
    const float* bo3 = (const float*)d_in[17];
    float* y = (float*)d_out;

    // workspace (floats): u | mbuf | WpT(320x256) | Bpk(u32)
    float* u    = (float*)d_ws;
    float* mbuf = u    + (size_t)BT * STATE;
    float* WpT  = mbuf + (size_t)BT * MOTOR;
    u32*   Bpk  = (u32*)(WpT + (size_t)(STATE + MOTOR) * STATE);

    int prep_items = BPK_TOTAL + STATE*STATE + STATE*MOTOR;
    prep_kernel<<<(prep_items + 255)/256, 256, 0, stream>>>(
        Wi1, Wi2, Wi3, Wih, Wo1, Wo2, Wo3, Whh, Who, Bpk, WpT);
    encoder_mfma<<<BT/64, 256, 0, stream>>>(x, Bpk, bi1, bi2, bi3, bh, u);
    rnn_kernel<<<BB, 512, 0, stream>>>(u, WpT, bo, mbuf);
    decoder_mfma<<<BT/64, 256, 0, stream>>>(mbuf, Bpk, bo1, bo2, bo3, y);
}

// Round 15
// 669.869 us; speedup vs baseline: 1.2415x; 1.2415x over previous
//
#include <hip/hip_runtime.h>
#include <hip/hip_bf16.h>
#include <cstddef>

// Problem constants
#define BB    256
#define TT    512
#define DIN   64
#define H1    256
#define INTER 128
#define STATE 256
#define MOTOR 64
#define DOUT  32
#define BT    (BB*TT)   // 131072

typedef unsigned int u32;
typedef short short8 __attribute__((ext_vector_type(8)));
typedef float f32x4  __attribute__((ext_vector_type(4)));

// Packed-weight (hi/lo bf16 in one u32) fragment-order offsets, in u32 elems
#define OFF_I1 0         // Wi1: 64x256   -> 16384
#define OFF_I2 16384     // Wi2: 256x256  -> 65536
#define OFF_I3 81920     // Wi3: 256x128  -> 32768
#define OFF_IH 114688    // Wih: 128x256  -> 32768
#define OFF_O1 147456    // Wo1: 64x256   -> 16384
#define OFF_O2 163840    // Wo2: 256x256  -> 65536
#define OFF_O3 229376    // Wo3: 256x32   -> 8192
#define BPK_TOTAL 237568

__device__ __forceinline__ float tanh_fast(float x) {
    float e = __expf(2.0f * x);
    return 1.0f - 2.0f / (e + 1.0f);
}

__device__ __forceinline__ u32 f2u(float f){ union{float f; u32 u;} v; v.f=f; return v.u; }
__device__ __forceinline__ float u2f(u32 u){ union{u32 u; float f;} v; v.u=u; return v.f; }

// fp32 -> packed (hi bf16 in [15:0], residual-lo bf16 in [31:16]), RNE both.
__device__ __forceinline__ u32 packhl(float x) {
    u32 b  = f2u(x);
    u32 hi = (b + 0x7fffu + ((b >> 16) & 1u)) >> 16;
    float lo = x - u2f(hi << 16);
    u32 bl = f2u(lo);
    u32 l16 = (bl + 0x7fffu + ((bl >> 16) & 1u)) >> 16;
    return (hi & 0xffffu) | (l16 << 16);
}

// 8 packed u32 -> hi-frag / lo-frag (each 8 bf16 as short8)
__device__ __forceinline__ void unpack8(uint4 w0, uint4 w1, short8& hi, short8& lo) {
    union { u32 u[4]; short8 s; } H, L;
    H.u[0] = __builtin_amdgcn_perm(w0.y, w0.x, 0x05040100u);
    L.u[0] = __builtin_amdgcn_perm(w0.y, w0.x, 0x07060302u);
    H.u[1] = __builtin_amdgcn_perm(w0.w, w0.z, 0x05040100u);
    L.u[1] = __builtin_amdgcn_perm(w0.w, w0.z, 0x07060302u);
    H.u[2] = __builtin_amdgcn_perm(w1.y, w1.x, 0x05040100u);
    L.u[2] = __builtin_amdgcn_perm(w1.y, w1.x, 0x07060302u);
    H.u[3] = __builtin_amdgcn_perm(w1.w, w1.z, 0x05040100u);
    L.u[3] = __builtin_amdgcn_perm(w1.w, w1.z, 0x07060302u);
    hi = H.s; lo = L.s;
}

// LDS activation addressing: [64 rows][256 words], XOR-swizzled in 16B units.
__device__ __forceinline__ int swz(int row, int col) {
    return row * 256 + (col ^ ((row & 7) << 2));
}

// ---------------------------------------------------------------------------
// One MFMA MLP layer over a 64-token tile held in LDS (packed hi/lo u32).
//   Split-bf16: D += Ahi*Bhi + Ahi*Blo + Alo*Bhi  (~fp32 accuracy).
// v15: 8 waves/block (wv = 0..7). Wave wv owns col-frags [wv*NFW, ...)
// with NFW = NF/8 (small-N layers idle upper waves). Per-wave acc halves
// vs the 4-wave version -> lower VGPR, 2x waves to hide LDS/B-load latency.
// ---------------------------------------------------------------------------
template<int K, int N, bool TANH, bool TOGLOBAL>
__device__ __forceinline__ void mfma_layer(
    const u32* __restrict__ Bpk, const float* __restrict__ bias,
    const u32* inB, u32* outB, float* __restrict__ gout,
    int lane, int wv)
{
    constexpr int NF  = N / 16;
    constexpr int NFW = (NF >= 8) ? NF / 8 : 1;
    constexpr int KC  = K / 32;
    const int q = lane >> 4, c = lane & 15;
    const int nf0 = wv * NFW;
    if (nf0 >= NF) return;   // small-N layers idle the upper waves

    f32x4 acc[4][NFW];
    #pragma unroll
    for (int nf = 0; nf < NFW; ++nf) {
        float bv = bias[(nf0 + nf) * 16 + c];
        #pragma unroll
        for (int rf = 0; rf < 4; ++rf) acc[rf][nf] = (f32x4){bv, bv, bv, bv};
    }

    #pragma unroll 2
    for (int kc = 0; kc < KC; ++kc) {
        short8 ahi[4], alo[4];
        #pragma unroll
        for (int rf = 0; rf < 4; ++rf) {
            int row = rf * 16 + c;
            int kb  = kc * 32 + q * 8;
            int m4  = (row & 7) << 2;
            uint4 w0 = *(const uint4*)(inB + row * 256 + ( kb      ^ m4));
            uint4 w1 = *(const uint4*)(inB + row * 256 + ((kb + 4) ^ m4));
            unpack8(w0, w1, ahi[rf], alo[rf]);
        }
        #pragma unroll
        for (int nf = 0; nf < NFW; ++nf) {
            const u32* bp = Bpk + (((size_t)(kc * NF + nf0 + nf) * 64 + lane) * 8);
            uint4 b0 = *(const uint4*)bp;
            uint4 b1 = *(const uint4*)(bp + 4);
            short8 bhi, blo; unpack8(b0, b1, bhi, blo);
            #pragma unroll
            for (int rf = 0; rf < 4; ++rf) {
                acc[rf][nf] = __builtin_amdgcn_mfma_f32_16x16x32_bf16(ahi[rf], bhi, acc[rf][nf], 0, 0, 0);
                acc[rf][nf] = __builtin_amdgcn_mfma_f32_16x16x32_bf16(ahi[rf], blo, acc[rf][nf], 0, 0, 0);
                acc[rf][nf] = __builtin_amdgcn_mfma_f32_16x16x32_bf16(alo[rf], bhi, acc[rf][nf], 0, 0, 0);
            }
        }
    }

    #pragma unroll
    for (int rf = 0; rf < 4; ++rf) {
        #pragma unroll
        for (int nf = 0; nf < NFW; ++nf) {
            #pragma unroll
            for (int r = 0; r < 4; ++r) {
                float v = acc[rf][nf][r];
                if (TANH) v = tanh_fast(v);
                int row = rf * 16 + q * 4 + r;
                int col = (nf0 + nf) * 16 + c;
                if (TOGLOBAL) gout[(size_t)row * N + col] = v;
                else          outB[swz(row, col)] = packhl(v);
            }
        }
    }
}

// Stage a [64 tokens][64 cols] fp32 global tile into packed LDS (cols 0..63).
// v15: 512 threads -> 2 iterations of 32 token-rows.
__device__ __forceinline__ void stage64(const float* __restrict__ src, u32* dst, int tid) {
    int tt = tid >> 4;          // 0..31
    int c4 = (tid & 15) * 4;
    #pragma unroll
    for (int i = 0; i < 2; ++i) {
        int tok = tt + 32 * i;
        float4 v = *(const float4*)(src + (size_t)tok * 64 + c4);
        uint4 p;
        p.x = packhl(v.x); p.y = packhl(v.y); p.z = packhl(v.z); p.w = packhl(v.w);
        *(uint4*)(dst + swz(tok, c4)) = p;
    }
}

// ---------------------------------------------------------------------------
// prep: pack all MLP weights into MFMA-fragment order (hi/lo u32), and build
// WpT = [Whh^T (256 rows) ; Who^T (64 rows)], each row 256 floats.
// ---------------------------------------------------------------------------
__global__ __launch_bounds__(256) void prep_kernel(
    const float* __restrict__ Wi1, const float* __restrict__ Wi2,
    const float* __restrict__ Wi3, const float* __restrict__ Wih,
    const float* __restrict__ Wo1, const float* __restrict__ Wo2,
    const float* __restrict__ Wo3,
    const float* __restrict__ Whh, const float* __restrict__ Who,
    u32* __restrict__ Bpk, float* __restrict__ WpT)
{
    int idx = blockIdx.x * 256 + threadIdx.x;
    if (idx < BPK_TOTAL) {
        const float* W; int NF; int i = idx;
        if      (i < OFF_I2) { W = Wi1; NF = 16; i -= OFF_I1; }
        else if (i < OFF_I3) { W = Wi2; NF = 16; i -= OFF_I2; }
        else if (i < OFF_IH) { W = Wi3; NF = 8;  i -= OFF_I3; }
        else if (i < OFF_O1) { W = Wih; NF = 16; i -= OFF_IH; }
        else if (i < OFF_O2) { W = Wo1; NF = 16; i -= OFF_O1; }
        else if (i < OFF_O3) { W = Wo2; NF = 16; i -= OFF_O2; }
        else                 { W = Wo3; NF = 2;  i -= OFF_O3; }
        int e = i & 7, l = (i >> 3) & 63, t = i >> 9;
        int nf = t % NF, kc = t / NF;
        int k = kc * 32 + ((l >> 4) * 8) + e;
        int n = nf * 16 + (l & 15);
        Bpk[idx] = packhl(W[(size_t)k * (NF * 16) + n]);
    } else if (idx < BPK_TOTAL + STATE*STATE) {
        int i = idx - BPK_TOTAL; int j = i >> 8, n = i & 255;
        WpT[n * STATE + j] = Whh[j * STATE + n];
    } else if (idx < BPK_TOTAL + STATE*STATE + STATE*MOTOR) {
        int i = idx - BPK_TOTAL - STATE*STATE; int j = i >> 6, o = i & 63;
        WpT[(size_t)(STATE + o) * STATE + j] = Who[j * MOTOR + o];
    }
}

// ---------------------------------------------------------------------------
// MFMA encoder: x -> tanh(Wi1) -> tanh(Wi2) -> Wi3 -> (Wih + bh) = u
// v15: 512 threads (8 waves) per 64-token block -> 2x latency hiding.
// ---------------------------------------------------------------------------
__global__ __launch_bounds__(512, 1) void encoder_mfma(
    const float* __restrict__ x, const u32* __restrict__ Bpk,
    const float* __restrict__ bi1, const float* __restrict__ bi2,
    const float* __restrict__ bi3, const float* __restrict__ bh,
    float* __restrict__ u)
{
    __shared__ u32 buf0[64 * 256];
    __shared__ u32 buf1[64 * 256];
    const int tid = threadIdx.x, lane = tid & 63, wv = tid >> 6;
    const size_t row0 = (size_t)blockIdx.x * 64;

    stage64(x + row0 * DIN, buf0, tid);
    __syncthreads();
    mfma_layer<DIN,  H1,    true,  false>(Bpk + OFF_I1, bi1, buf0, buf1, nullptr, lane, wv);
    __syncthreads();
    mfma_layer<H1,   H1,    true,  false>(Bpk + OFF_I2, bi2, buf1, buf0, nullptr, lane, wv);
    __syncthreads();
    mfma_layer<H1,   INTER, false, false>(Bpk + OFF_I3, bi3, buf0, buf1, nullptr, lane, wv);
    __syncthreads();
    mfma_layer<INTER,STATE, false, true >(Bpk + OFF_IH, bh,  buf1, nullptr, u + row0 * STATE, lane, wv);
}

// ---------------------------------------------------------------------------
// MFMA decoder: m -> tanh(Wo1) -> tanh(Wo2) -> Wo3 -> y   (512 threads)
// ---------------------------------------------------------------------------
__global__ __launch_bounds__(512, 1) void decoder_mfma(
    const float* __restrict__ m, const u32* __restrict__ Bpk,
    const float* __restrict__ bo1, const float* __restrict__ bo2,
    const float* __restrict__ bo3,
    float* __restrict__ y)
{
    __shared__ u32 buf0[64 * 256];
    __shared__ u32 buf1[64 * 256];
    const int tid = threadIdx.x, lane = tid & 63, wv = tid >> 6;
    const size_t row0 = (size_t)blockIdx.x * 64;

    stage64(m + row0 * MOTOR, buf0, tid);
    __syncthreads();
    mfma_layer<MOTOR, H1,   true,  false>(Bpk + OFF_O1, bo1, buf0, buf1, nullptr, lane, wv);
    __syncthreads();
    mfma_layer<H1,    H1,   true,  false>(Bpk + OFF_O2, bo2, buf1, buf0, nullptr, lane, wv);
    __syncthreads();
    mfma_layer<H1,    DOUT, false, true >(Bpk + OFF_O3, bo3, buf0, nullptr, y + row0 * DOUT, lane, wv);
}

// ---------------------------------------------------------------------------
// RNN scan v11 (reverted verbatim — best measured: 445 us).
// 256 blocks x 1 sample, 512 threads (8 waves, 2/SIMD), 1 barrier/step.
// Six structural attacks (v12-v14: pk_fma, DPP reduce, burst regroup) all
// measured flat-or-worse => this is the dependency pattern's floor
// (~2100 cyc/step: barrier-lockstep + DS broadcast + serial chain).
// ---------------------------------------------------------------------------
__global__ __launch_bounds__(512, 2) void rnn_kernel(
    const float* __restrict__ u,      // [B*T, STATE]
    const float* __restrict__ WpT,    // [320][256] = [WhhT ; WhoT]
    const float* __restrict__ bo,     // [MOTOR]
    float* __restrict__ m)            // [B*T, MOTOR]
{
    __shared__ float hb[2][STATE];
    __shared__ float part[64 * 44];   // [g][o][s] : g*44 + o*8 + s

    const int tid   = threadIdx.x;
    const int b     = blockIdx.x;
    const int s     = tid & 7;
    const int g     = tid >> 3;          // 0..63
    const int kbase = s * 32;

    // --- weights -> registers (once), UNIFORM shape/order across threads ---
    // o=0..3: Whh rows 4g+o ; o=4: Who row g (WpT row 256+g). 160 floats.
    float4 wq[5][8];
    #pragma unroll
    for (int o = 0; o < 5; ++o) {
        const int row = (o < 4) ? (4 * g + o) : (STATE + g);
        const float* wr = WpT + (size_t)row * STATE + kbase;
        #pragma unroll
        for (int ii = 0; ii < 8; ++ii)
            wq[o][ii] = *(const float4*)(wr + 4 * ((ii + s) & 7));
    }

    // --- precomputed rotated h-read pointers (both buffers) ---
    const float4* hp0[8];
    const float4* hp1[8];
    #pragma unroll
    for (int ii = 0; ii < 8; ++ii) {
        int off = kbase + 4 * ((ii + s) & 7);
        hp0[ii] = (const float4*)(hb[0] + off);
        hp1[ii] = (const float4*)(hb[1] + off);
    }

    const bool ish  = (s < 4);           // reducer lane for h-row hidx
    const int  hidx = 4 * g + (s & 3);
    const int  pb   = g * 44 + s * 8;    // set base this lane reduces (s<5)

    const float bov  = (s == 4) ? bo[g] : 0.f;
    const float* ubase = u + (size_t)b * TT * STATE + hidx;   // ish lanes
    float*       mst   = m + (size_t)b * TT * MOTOR + g;      // s==4 cursor

    if (tid < STATE) hb[0][tid] = 0.f;
    float up = ish ? ubase[0] : 0.f;   // u_0
    __syncthreads();

    // body: read h_{t-1} via HP (compile-time buffer), publish h_t to HWR.
#define RNN_BODY(T, HP, HWR)                                                   \
    {                                                                          \
        float upn = 0.f;                                                       \
        if (ish && (T) + 1 < TT) upn = ubase[(size_t)((T) + 1) * STATE];       \
        float a0 = 0.f, a1 = 0.f, a2 = 0.f, a3 = 0.f, a4 = 0.f;                \
        _Pragma("unroll")                                                      \
        for (int ii = 0; ii < 8; ++ii) {                                       \
            float4 hv = *HP[ii];                                               \
            a0 = fmaf(wq[0][ii].x, hv.x, a0); a0 = fmaf(wq[0][ii].y, hv.y, a0);\
            a0 = fmaf(wq[0][ii].z, hv.z, a0); a0 = fmaf(wq[0][ii].w, hv.w, a0);\
            a1 = fmaf(wq[1][ii].x, hv.x, a1); a1 = fmaf(wq[1][ii].y, hv.y, a1);\
            a1 = fmaf(wq[1][ii].z, hv.z, a1); a1 = fmaf(wq[1][ii].w, hv.w, a1);\
            a2 = fmaf(wq[2][ii].x, hv.x, a2); a2 = fmaf(wq[2][ii].y, hv.y, a2);\
            a2 = fmaf(wq[2][ii].z, hv.z, a2); a2 = fmaf(wq[2][ii].w, hv.w, a2);\
            a3 = fmaf(wq[3][ii].x, hv.x, a3); a3 = fmaf(wq[3][ii].y, hv.y, a3);\
            a3 = fmaf(wq[3][ii].z, hv.z, a3); a3 = fmaf(wq[3][ii].w, hv.w, a3);\
            a4 = fmaf(wq[4][ii].x, hv.x, a4); a4 = fmaf(wq[4][ii].y, hv.y, a4);\
            a4 = fmaf(wq[4][ii].z, hv.z, a4); a4 = fmaf(wq[4][ii].w, hv.w, a4);\
        }                                                                      \
        part[g * 44 +  0 + s] = a0;                                            \
        part[g * 44 +  8 + s] = a1;                                            \
        part[g * 44 + 16 + s] = a2;                                            \
        part[g * 44 + 24 + s] = a3;                                            \
        part[g * 44 + 32 + s] = a4;                                            \
        if (s < 5) {                                                           \
            float4 pA = *(const float4*)(part + pb);                           \
            float4 pB = *(const float4*)(part + pb + 4);                       \
            float v = ((pA.x + pA.y) + (pA.z + pA.w))                          \
                    + ((pB.x + pB.y) + (pB.z + pB.w));                         \
            if (ish) {                                                         \
                if ((T) < TT) HWR[hidx] = tanh_fast(v + up);                   \
            } else if ((T) > 0) {                                              \
                mst[0] = v + bov;                                              \
                mst += MOTOR;                                                  \
            }                                                                  \
        }                                                                      \
        __syncthreads();                                                       \
        up = upn;                                                              \
    }

    for (int t = 0; t <= TT; t += 2) {
        RNN_BODY(t,     hp0, (hb[1]));      // even t: read hb0, write hb1
        if (t + 1 <= TT)
            RNN_BODY(t + 1, hp1, (hb[0]));  // odd t: read hb1, write hb0
    }
#undef RNN_BODY
}

// ---------------------------------------------------------------------------
extern "C" void kernel_launch(void* const* d_in, const int* in_sizes, int n_in,
                              void* d_out, int out_size, void* d_ws, size_t ws_size,
                              hipStream_t stream) {
    const float* x   = (const float*)d_in[0];
    const float* Wi1 = (const float*)d_in[1];
    const float* bi1 = (const float*)d_in[2];
    const float* Wi2 = (const float*)d_in[3];
    const float* bi2 = (const float*)d_in[4];
    const float* Wi3 = (const float*)d_in[5];
    const float* bi3 = (const float*)d_in[6];
    const float* Wih = (const float*)d_in[7];
    const float* Whh = (const float*)d_in[8];
    const float* bh  = (const float*)d_in[9];
    const float* Who = (const float*)d_in[10];
    const float* bo  = (const float*)d_in[11];
    const float* Wo1 = (const float*)d_in[12];
    const float* bo1 = (const float*)d_in[13];
    const float* Wo2 = (const float*)d_in[14];
    const float* bo2 = (const float*)d_in[15];
    const float* Wo3 = (const float*)d_in[16];
    const float* bo3 = (const float*)d_in[17];
    float* y = (float*)d_out;

    // workspace (floats): u | mbuf | WpT(320x256) | Bpk(u32)
    float* u    = (float*)d_ws;
    float* mbuf = u    + (size_t)BT * STATE;
    float* WpT  = mbuf + (size_t)BT * MOTOR;
    u32*   Bpk  = (u32*)(WpT + (size_t)(STATE + MOTOR) * STATE);

    int prep_items = BPK_TOTAL + STATE*STATE + STATE*MOTOR;
    prep_kernel<<<(prep_items + 255)/256, 256, 0, stream>>>(
        Wi1, Wi2, Wi3, Wih, Wo1, Wo2, Wo3, Whh, Who, Bpk, WpT);
    encoder_mfma<<<BT/64, 512, 0, stream>>>(x, Bpk, bi1, bi2, bi3, bh, u);
    rnn_kernel<<<BB, 512, 0, stream>>>(u, WpT, bo, mbuf);
    decoder_mfma<<<BT/64, 512, 0, stream>>>(mbuf, Bpk, bo1, bo2, bo3, y);
}

// Round 16
// 564.017 us; speedup vs baseline: 1.4745x; 1.1877x over previous
//
#include <hip/hip_runtime.h>
#include <hip/hip_bf16.h>
#include <cstddef>

// Problem constants
#define BB    256
#define TT    512
#define DIN   64
#define H1    256
#define INTER 128
#define STATE 256
#define MOTOR 64
#define DOUT  32
#define BT    (BB*TT)   // 131072

typedef unsigned int u32;
typedef short short8 __attribute__((ext_vector_type(8)));
typedef float f32x4  __attribute__((ext_vector_type(4)));

// Packed-weight (hi/lo bf16 in one u32) fragment-order offsets, in u32 elems
#define OFF_I1 0         // Wi1: 64x256   -> 16384
#define OFF_I2 16384     // Wi2: 256x256  -> 65536
#define OFF_I3 81920     // Wi3: 256x128  -> 32768
#define OFF_IH 114688    // Wih: 128x256  -> 32768
#define OFF_O1 147456    // Wo1: 64x256   -> 16384
#define OFF_O2 163840    // Wo2: 256x256  -> 65536
#define OFF_O3 229376    // Wo3: 256x32   -> 8192
#define BPK_TOTAL 237568

__device__ __forceinline__ float tanh_fast(float x) {
    float e = __expf(2.0f * x);
    return 1.0f - 2.0f / (e + 1.0f);
}

__device__ __forceinline__ u32 f2u(float f){ union{float f; u32 u;} v; v.f=f; return v.u; }
__device__ __forceinline__ float u2f(u32 u){ union{u32 u; float f;} v; v.u=u; return v.f; }

__device__ __forceinline__ unsigned short bf16rne(float x) {
    u32 b = f2u(x);
    return (unsigned short)((b + 0x7fffu + ((b >> 16) & 1u)) >> 16);
}

// fp32 -> packed (hi bf16 in [15:0], residual-lo bf16 in [31:16]), RNE both.
__device__ __forceinline__ u32 packhl(float x) {
    u32 b  = f2u(x);
    u32 hi = (b + 0x7fffu + ((b >> 16) & 1u)) >> 16;
    float lo = x - u2f(hi << 16);
    u32 bl = f2u(lo);
    u32 l16 = (bl + 0x7fffu + ((bl >> 16) & 1u)) >> 16;
    return (hi & 0xffffu) | (l16 << 16);
}

// 8 packed u32 -> hi-frag / lo-frag (each 8 bf16 as short8) — B (weights) only
__device__ __forceinline__ void unpack8(uint4 w0, uint4 w1, short8& hi, short8& lo) {
    union { u32 u[4]; short8 s; } H, L;
    H.u[0] = __builtin_amdgcn_perm(w0.y, w0.x, 0x05040100u);
    L.u[0] = __builtin_amdgcn_perm(w0.y, w0.x, 0x07060302u);
    H.u[1] = __builtin_amdgcn_perm(w0.w, w0.z, 0x05040100u);
    L.u[1] = __builtin_amdgcn_perm(w0.w, w0.z, 0x07060302u);
    H.u[2] = __builtin_amdgcn_perm(w1.y, w1.x, 0x05040100u);
    L.u[2] = __builtin_amdgcn_perm(w1.y, w1.x, 0x07060302u);
    H.u[3] = __builtin_amdgcn_perm(w1.w, w1.z, 0x05040100u);
    L.u[3] = __builtin_amdgcn_perm(w1.w, w1.z, 0x07060302u);
    hi = H.s; lo = L.s;
}

// v16 activation LDS: bf16 [64 rows][256 cols] = [64][128] u32, 32 KB.
// Swizzle: XOR the 16B-granule index (u32-offset bits 2..4) with (row&7).
__device__ __forceinline__ int swzu(int row, int cu) {   // cu = u32 offset in row
    return row * 128 + (cu ^ ((row & 7) << 2));
}

// ---------------------------------------------------------------------------
// One MFMA MLP layer over a 64-token bf16 tile held IN-PLACE in LDS.
//   D += Ahi*Bhi + Ahi*Blo   (A = bf16 activations — Alo == 0 by storage;
//   B = exact hi/lo split weights). 8 waves; wave wv owns NFW = NF/8 col-
//   frags (small-N layers idle upper waves but still hit the barriers).
//   Internal: [reads] -> barrier -> [in-place writes] -> barrier.
// ---------------------------------------------------------------------------
template<int K, int N, bool TANH, bool TOGLOBAL>
__device__ __forceinline__ void mfma_layer(
    const u32* __restrict__ Bpk, const float* __restrict__ bias,
    u32* buf, float* __restrict__ gout,
    int lane, int wv)
{
    constexpr int NF  = N / 16;
    constexpr int NFW = (NF >= 8) ? NF / 8 : 1;
    constexpr int KC  = K / 32;
    const int q = lane >> 4, c = lane & 15;
    const int nf0 = wv * NFW;
    const bool active = (nf0 < NF);

    f32x4 acc[4][NFW];
    if (active) {
        #pragma unroll
        for (int nf = 0; nf < NFW; ++nf) {
            float bv = bias[(nf0 + nf) * 16 + c];
            #pragma unroll
            for (int rf = 0; rf < 4; ++rf) acc[rf][nf] = (f32x4){bv, bv, bv, bv};
        }
        #pragma unroll 2
        for (int kc = 0; kc < KC; ++kc) {
            short8 a[4];                       // A-frags: direct bf16, no unpack
            #pragma unroll
            for (int rf = 0; rf < 4; ++rf) {
                int row = rf * 16 + c;
                a[rf] = *(const short8*)(buf + swzu(row, kc * 16 + q * 4));
            }
            #pragma unroll
            for (int nf = 0; nf < NFW; ++nf) {
                const u32* bp = Bpk + (((size_t)(kc * NF + nf0 + nf) * 64 + lane) * 8);
                uint4 b0 = *(const uint4*)bp;
                uint4 b1 = *(const uint4*)(bp + 4);
                short8 bhi, blo; unpack8(b0, b1, bhi, blo);
                #pragma unroll
                for (int rf = 0; rf < 4; ++rf) {
                    acc[rf][nf] = __builtin_amdgcn_mfma_f32_16x16x32_bf16(a[rf], bhi, acc[rf][nf], 0, 0, 0);
                    acc[rf][nf] = __builtin_amdgcn_mfma_f32_16x16x32_bf16(a[rf], blo, acc[rf][nf], 0, 0, 0);
                }
            }
        }
    }
    __syncthreads();   // all reads of buf complete before in-place overwrite

    if (active) {
        #pragma unroll
        for (int rf = 0; rf < 4; ++rf) {
            #pragma unroll
            for (int nf = 0; nf < NFW; ++nf) {
                #pragma unroll
                for (int r = 0; r < 4; ++r) {
                    float v = acc[rf][nf][r];
                    if (TANH) v = tanh_fast(v);
                    int row = rf * 16 + q * 4 + r;
                    int col = (nf0 + nf) * 16 + c;
                    if (TOGLOBAL) {
                        gout[(size_t)row * N + col] = v;
                    } else {
                        int cu = (col >> 1) ^ ((row & 7) << 2);
                        ((unsigned short*)buf)[(row * 128 + cu) * 2 + (col & 1)] = bf16rne(v);
                    }
                }
            }
        }
    }
    __syncthreads();   // writes visible to next layer
}

// Stage a [64 tokens][64 cols] fp32 global tile into bf16 LDS (cols 0..63).
// 512 threads -> 2 iterations of 32 token-rows; uint2 (2x packed bf16) writes.
__device__ __forceinline__ void stage64(const float* __restrict__ src, u32* dst, int tid) {
    int tt = tid >> 4;          // 0..31
    int c4 = (tid & 15) * 4;
    #pragma unroll
    for (int i = 0; i < 2; ++i) {
        int tok = tt + 32 * i;
        float4 v = *(const float4*)(src + (size_t)tok * 64 + c4);
        u32 p0 = (u32)bf16rne(v.x) | ((u32)bf16rne(v.y) << 16);
        u32 p1 = (u32)bf16rne(v.z) | ((u32)bf16rne(v.w) << 16);
        int cu = (c4 >> 1) ^ ((tok & 7) << 2);
        *(uint2*)(dst + tok * 128 + cu) = make_uint2(p0, p1);
    }
}

// ---------------------------------------------------------------------------
// prep: pack all MLP weights into MFMA-fragment order (hi/lo u32), and build
// WpT = [Whh^T (256 rows) ; Who^T (64 rows)], each row 256 floats.
// ---------------------------------------------------------------------------
__global__ __launch_bounds__(256) void prep_kernel(
    const float* __restrict__ Wi1, const float* __restrict__ Wi2,
    const float* __restrict__ Wi3, const float* __restrict__ Wih,
    const float* __restrict__ Wo1, const float* __restrict__ Wo2,
    const float* __restrict__ Wo3,
    const float* __restrict__ Whh, const float* __restrict__ Who,
    u32* __restrict__ Bpk, float* __restrict__ WpT)
{
    int idx = blockIdx.x * 256 + threadIdx.x;
    if (idx < BPK_TOTAL) {
        const float* W; int NF; int i = idx;
        if      (i < OFF_I2) { W = Wi1; NF = 16; i -= OFF_I1; }
        else if (i < OFF_I3) { W = Wi2; NF = 16; i -= OFF_I2; }
        else if (i < OFF_IH) { W = Wi3; NF = 8;  i -= OFF_I3; }
        else if (i < OFF_O1) { W = Wih; NF = 16; i -= OFF_IH; }
        else if (i < OFF_O2) { W = Wo1; NF = 16; i -= OFF_O1; }
        else if (i < OFF_O3) { W = Wo2; NF = 16; i -= OFF_O2; }
        else                 { W = Wo3; NF = 2;  i -= OFF_O3; }
        int e = i & 7, l = (i >> 3) & 63, t = i >> 9;
        int nf = t % NF, kc = t / NF;
        int k = kc * 32 + ((l >> 4) * 8) + e;
        int n = nf * 16 + (l & 15);
        Bpk[idx] = packhl(W[(size_t)k * (NF * 16) + n]);
    } else if (idx < BPK_TOTAL + STATE*STATE) {
        int i = idx - BPK_TOTAL; int j = i >> 8, n = i & 255;
        WpT[n * STATE + j] = Whh[j * STATE + n];
    } else if (idx < BPK_TOTAL + STATE*STATE + STATE*MOTOR) {
        int i = idx - BPK_TOTAL - STATE*STATE; int j = i >> 6, o = i & 63;
        WpT[(size_t)(STATE + o) * STATE + j] = Who[j * MOTOR + o];
    }
}

// ---------------------------------------------------------------------------
// MFMA encoder: x -> tanh(Wi1) -> tanh(Wi2) -> Wi3 -> (Wih + bh) = u
// v16: single 32 KB in-place bf16 buffer, 512 threads -> 2-4 blocks/CU.
// ---------------------------------------------------------------------------
__global__ __launch_bounds__(512, 4) void encoder_mfma(
    const float* __restrict__ x, const u32* __restrict__ Bpk,
    const float* __restrict__ bi1, const float* __restrict__ bi2,
    const float* __restrict__ bi3, const float* __restrict__ bh,
    float* __restrict__ u)
{
    __shared__ u32 buf[64 * 128];   // 32 KB bf16 activations
    const int tid = threadIdx.x, lane = tid & 63, wv = tid >> 6;
    const size_t row0 = (size_t)blockIdx.x * 64;

    stage64(x + row0 * DIN, buf, tid);
    __syncthreads();
    mfma_layer<DIN,  H1,    true,  false>(Bpk + OFF_I1, bi1, buf, nullptr, lane, wv);
    mfma_layer<H1,   H1,    true,  false>(Bpk + OFF_I2, bi2, buf, nullptr, lane, wv);
    mfma_layer<H1,   INTER, false, false>(Bpk + OFF_I3, bi3, buf, nullptr, lane, wv);
    mfma_layer<INTER,STATE, false, true >(Bpk + OFF_IH, bh,  buf, u + row0 * STATE, lane, wv);
}

// ---------------------------------------------------------------------------
// MFMA decoder: m -> tanh(Wo1) -> tanh(Wo2) -> Wo3 -> y   (same structure)
// ---------------------------------------------------------------------------
__global__ __launch_bounds__(512, 4) void decoder_mfma(
    const float* __restrict__ m, const u32* __restrict__ Bpk,
    const float* __restrict__ bo1, const float* __restrict__ bo2,
    const float* __restrict__ bo3,
    float* __restrict__ y)
{
    __shared__ u32 buf[64 * 128];   // 32 KB
    const int tid = threadIdx.x, lane = tid & 63, wv = tid >> 6;
    const size_t row0 = (size_t)blockIdx.x * 64;

    stage64(m + row0 * MOTOR, buf, tid);
    __syncthreads();
    mfma_layer<MOTOR, H1,   true,  false>(Bpk + OFF_O1, bo1, buf, nullptr, lane, wv);
    mfma_layer<H1,    H1,   true,  false>(Bpk + OFF_O2, bo2, buf, nullptr, lane, wv);
    mfma_layer<H1,    DOUT, false, true >(Bpk + OFF_O3, bo3, buf, y + row0 * DOUT, lane, wv);
}

// ---------------------------------------------------------------------------
// RNN scan v11 (best measured: 445 us — structural floor, 6 attacks falsified).
// 256 blocks x 1 sample, 512 threads (8 waves, 2/SIMD), 1 barrier/step.
// ---------------------------------------------------------------------------
__global__ __launch_bounds__(512, 2) void rnn_kernel(
    const float* __restrict__ u,      // [B*T, STATE]
    const float* __restrict__ WpT,    // [320][256] = [WhhT ; WhoT]
    const float* __restrict__ bo,     // [MOTOR]
    float* __restrict__ m)            // [B*T, MOTOR]
{
    __shared__ float hb[2][STATE];
    __shared__ float part[64 * 44];   // [g][o][s] : g*44 + o*8 + s

    const int tid   = threadIdx.x;
    const int b     = blockIdx.x;
    const int s     = tid & 7;
    const int g     = tid >> 3;          // 0..63
    const int kbase = s * 32;

    // --- weights -> registers (once), UNIFORM shape/order across threads ---
    float4 wq[5][8];
    #pragma unroll
    for (int o = 0; o < 5; ++o) {
        const int row = (o < 4) ? (4 * g + o) : (STATE + g);
        const float* wr = WpT + (size_t)row * STATE + kbase;
        #pragma unroll
        for (int ii = 0; ii < 8; ++ii)
            wq[o][ii] = *(const float4*)(wr + 4 * ((ii + s) & 7));
    }

    // --- precomputed rotated h-read pointers (both buffers) ---
    const float4* hp0[8];
    const float4* hp1[8];
    #pragma unroll
    for (int ii = 0; ii < 8; ++ii) {
        int off = kbase + 4 * ((ii + s) & 7);
        hp0[ii] = (const float4*)(hb[0] + off);
        hp1[ii] = (const float4*)(hb[1] + off);
    }

    const bool ish  = (s < 4);           // reducer lane for h-row hidx
    const int  hidx = 4 * g + (s & 3);
    const int  pb   = g * 44 + s * 8;    // set base this lane reduces (s<5)

    const float bov  = (s == 4) ? bo[g] : 0.f;
    const float* ubase = u + (size_t)b * TT * STATE + hidx;   // ish lanes
    float*       mst   = m + (size_t)b * TT * MOTOR + g;      // s==4 cursor

    if (tid < STATE) hb[0][tid] = 0.f;
    float up = ish ? ubase[0] : 0.f;   // u_0
    __syncthreads();

#define RNN_BODY(T, HP, HWR)                                                   \
    {                                                                          \
        float upn = 0.f;                                                       \
        if (ish && (T) + 1 < TT) upn = ubase[(size_t)((T) + 1) * STATE];       \
        float a0 = 0.f, a1 = 0.f, a2 = 0.f, a3 = 0.f, a4 = 0.f;                \
        _Pragma("unroll")                                                      \
        for (int ii = 0; ii < 8; ++ii) {                                       \
            float4 hv = *HP[ii];                                               \
            a0 = fmaf(wq[0][ii].x, hv.x, a0); a0 = fmaf(wq[0][ii].y, hv.y, a0);\
            a0 = fmaf(wq[0][ii].z, hv.z, a0); a0 = fmaf(wq[0][ii].w, hv.w, a0);\
            a1 = fmaf(wq[1][ii].x, hv.x, a1); a1 = fmaf(wq[1][ii].y, hv.y, a1);\
            a1 = fmaf(wq[1][ii].z, hv.z, a1); a1 = fmaf(wq[1][ii].w, hv.w, a1);\
            a2 = fmaf(wq[2][ii].x, hv.x, a2); a2 = fmaf(wq[2][ii].y, hv.y, a2);\
            a2 = fmaf(wq[2][ii].z, hv.z, a2); a2 = fmaf(wq[2][ii].w, hv.w, a2);\
            a3 = fmaf(wq[3][ii].x, hv.x, a3); a3 = fmaf(wq[3][ii].y, hv.y, a3);\
            a3 = fmaf(wq[3][ii].z, hv.z, a3); a3 = fmaf(wq[3][ii].w, hv.w, a3);\
            a4 = fmaf(wq[4][ii].x, hv.x, a4); a4 = fmaf(wq[4][ii].y, hv.y, a4);\
            a4 = fmaf(wq[4][ii].z, hv.z, a4); a4 = fmaf(wq[4][ii].w, hv.w, a4);\
        }                                                                      \
        part[g * 44 +  0 + s] = a0;                                            \
        part[g * 44 +  8 + s] = a1;                                            \
        part[g * 44 + 16 + s] = a2;                                            \
        part[g * 44 + 24 + s] = a3;                                            \
        part[g * 44 + 32 + s] = a4;                                            \
        if (s < 5) {                                                           \
            float4 pA = *(const float4*)(part + pb);                           \
            float4 pB = *(const float4*)(part + pb + 4);                       \
            float v = ((pA.x + pA.y) + (pA.z + pA.w))                          \
                    + ((pB.x + pB.y) + (pB.z + pB.w));                         \
            if (ish) {                                                         \
                if ((T) < TT) HWR[hidx] = tanh_fast(v + up);                   \
            } else if ((T) > 0) {                                              \
                mst[0] = v + bov;                                              \
                mst += MOTOR;                                                  \
            }                                                                  \
        }                                                                      \
        __syncthreads();                                                       \
        up = upn;                                                              \
    }

    for (int t = 0; t <= TT; t += 2) {
        RNN_BODY(t,     hp0, (hb[1]));      // even t: read hb0, write hb1
        if (t + 1 <= TT)
            RNN_BODY(t + 1, hp1, (hb[0]));  // odd t: read hb1, write hb0
    }
#undef RNN_BODY
}

// ---------------------------------------------------------------------------
extern "C" void kernel_launch(void* const* d_in, const int* in_sizes, int n_in,
                              void* d_out, int out_size, void* d_ws, size_t ws_size,
                              hipStream_t stream) {
    const float* x   = (const float*)d_in[0];
    const float* Wi1 = (const float*)d_in[1];
    const float* bi1 = (const float*)d_in[2];
    const float* Wi2 = (const float*)d_in[3];
    const float* bi2 = (const float*)d_in[4];
    const float* Wi3 = (const float*)d_in[5];
    const float* bi3 = (const float*)d_in[6];
    const float* Wih = (const float*)d_in[7];
    const float* Whh = (const float*)d_in[8];
    const float* bh  = (const float*)d_in[9];
    const float* Who = (const float*)d_in[10];
    const float* bo  = (const float*)d_in[11];
    const float* Wo1 = (const float*)d_in[12];
    const float* bo1 = (const float*)d_in[13];
    const float* Wo2 = (const float*)d_in[14];
    const float* bo2 = (const float*)d_in[15];
    const float* Wo3 = (const float*)d_in[16];
    const float* bo3 = (const float*)d_in[17];
    float* y = (float*)d_out;

    // workspace (floats): u | mbuf | WpT(320x256) | Bpk(u32)
    float* u    = (float*)d_ws;
    float* mbuf = u    + (size_t)BT * STATE;
    float* WpT  = mbuf + (size_t)BT * MOTOR;
    u32*   Bpk  = (u32*)(WpT + (size_t)(STATE + MOTOR) * STATE);

    int prep_items = BPK_TOTAL + STATE*STATE + STATE*MOTOR;
    prep_kernel<<<(prep_items + 255)/256, 256, 0, stream>>>(
        Wi1, Wi2, Wi3, Wih, Wo1, Wo2, Wo3, Whh, Who, Bpk, WpT);
    encoder_mfma<<<BT/64, 512, 0, stream>>>(x, Bpk, bi1, bi2, bi3, bh, u);
    rnn_kernel<<<BB, 512, 0, stream>>>(u, WpT, bo, mbuf);
    decoder_mfma<<<BT/64, 512, 0, stream>>>(mbuf, Bpk, bo1, bo2, bo3, y);
}

// Round 17
// 509.714 us; speedup vs baseline: 1.6316x; 1.1065x over previous
//
#include <hip/hip_runtime.h>
#include <hip/hip_bf16.h>
#include <cstddef>

// Problem constants
#define BB    256
#define TT    512
#define DIN   64
#define H1    256
#define INTER 128
#define STATE 256
#define MOTOR 64
#define DOUT  32
#define BT    (BB*TT)   // 131072

typedef unsigned int u32;
typedef unsigned short u16;
typedef short short8 __attribute__((ext_vector_type(8)));
typedef float f32x4  __attribute__((ext_vector_type(4)));

// bf16 weight-fragment offsets, in u16 elems (fragment order, 8 bf16/lane)
#define OFF_I1 0         // Wi1: 64x256   -> 16384
#define OFF_I2 16384     // Wi2: 256x256  -> 65536
#define OFF_I3 81920     // Wi3: 256x128  -> 32768
#define OFF_IH 114688    // Wih: 128x256  -> 32768
#define OFF_O1 147456    // Wo1: 64x256   -> 16384
#define OFF_O2 163840    // Wo2: 256x256  -> 65536
#define OFF_O3 229376    // Wo3: 256x32   -> 8192
#define BPK_TOTAL 237568

__device__ __forceinline__ float tanh_fast(float x) {
    float e = __expf(2.0f * x);
    return 1.0f - 2.0f / (e + 1.0f);
}

__device__ __forceinline__ u32 f2u(float f){ union{float f; u32 u;} v; v.f=f; return v.u; }

__device__ __forceinline__ u16 bf16rne(float x) {
    u32 b = f2u(x);
    return (u16)((b + 0x7fffu + ((b >> 16) & 1u)) >> 16);
}

// v16 activation LDS: bf16 [64 rows][256 cols] = [64][128] u32, 32 KB.
// Swizzle: XOR the 16B-granule index (u32-offset bits 2..4) with (row&7).
__device__ __forceinline__ int swzu(int row, int cu) {   // cu = u32 offset in row
    return row * 128 + (cu ^ ((row & 7) << 2));
}

// ---------------------------------------------------------------------------
// One MFMA MLP layer over a 64-token bf16 tile held IN-PLACE in LDS.
//   v17: B is plain bf16 (fragment-ordered) -> ONE MFMA per (rf,nf,kc),
//   no unpack, half the B bytes. A = bf16 activations (direct short8 reads).
//   8 waves; wave wv owns NFW = NF/8 col-frags (small-N layers idle upper
//   waves but still hit the barriers).
//   Internal: [reads] -> barrier -> [in-place writes] -> barrier.
// ---------------------------------------------------------------------------
template<int K, int N, bool TANH, bool TOGLOBAL>
__device__ __forceinline__ void mfma_layer(
    const u16* __restrict__ Bpk, const float* __restrict__ bias,
    u32* buf, float* __restrict__ gout,
    int lane, int wv)
{
    constexpr int NF  = N / 16;
    constexpr int NFW = (NF >= 8) ? NF / 8 : 1;
    constexpr int KC  = K / 32;
    const int q = lane >> 4, c = lane & 15;
    const int nf0 = wv * NFW;
    const bool active = (nf0 < NF);

    f32x4 acc[4][NFW];
    if (active) {
        #pragma unroll
        for (int nf = 0; nf < NFW; ++nf) {
            float bv = bias[(nf0 + nf) * 16 + c];
            #pragma unroll
            for (int rf = 0; rf < 4; ++rf) acc[rf][nf] = (f32x4){bv, bv, bv, bv};
        }
        #pragma unroll 2
        for (int kc = 0; kc < KC; ++kc) {
            short8 a[4];                       // A-frags: direct bf16
            #pragma unroll
            for (int rf = 0; rf < 4; ++rf) {
                int row = rf * 16 + c;
                a[rf] = *(const short8*)(buf + swzu(row, kc * 16 + q * 4));
            }
            #pragma unroll
            for (int nf = 0; nf < NFW; ++nf) {
                const u16* bp = Bpk + (((size_t)(kc * NF + nf0 + nf) * 64 + lane) * 8);
                short8 bb = *(const short8*)bp;   // one 16B load, no unpack
                #pragma unroll
                for (int rf = 0; rf < 4; ++rf)
                    acc[rf][nf] = __builtin_amdgcn_mfma_f32_16x16x32_bf16(a[rf], bb, acc[rf][nf], 0, 0, 0);
            }
        }
    }
    __syncthreads();   // all reads of buf complete before in-place overwrite

    if (active) {
        #pragma unroll
        for (int rf = 0; rf < 4; ++rf) {
            #pragma unroll
            for (int nf = 0; nf < NFW; ++nf) {
                #pragma unroll
                for (int r = 0; r < 4; ++r) {
                    float v = acc[rf][nf][r];
                    if (TANH) v = tanh_fast(v);
                    int row = rf * 16 + q * 4 + r;
                    int col = (nf0 + nf) * 16 + c;
                    if (TOGLOBAL) {
                        gout[(size_t)row * N + col] = v;
                    } else {
                        int cu = (col >> 1) ^ ((row & 7) << 2);
                        ((u16*)buf)[(row * 128 + cu) * 2 + (col & 1)] = bf16rne(v);
                    }
                }
            }
        }
    }
    __syncthreads();   // writes visible to next layer
}

// Stage a [64 tokens][64 cols] fp32 global tile into bf16 LDS (cols 0..63).
// 512 threads -> 2 iterations of 32 token-rows; uint2 (2x packed bf16) writes.
__device__ __forceinline__ void stage64(const float* __restrict__ src, u32* dst, int tid) {
    int tt = tid >> 4;          // 0..31
    int c4 = (tid & 15) * 4;
    #pragma unroll
    for (int i = 0; i < 2; ++i) {
        int tok = tt + 32 * i;
        float4 v = *(const float4*)(src + (size_t)tok * 64 + c4);
        u32 p0 = (u32)bf16rne(v.x) | ((u32)bf16rne(v.y) << 16);
        u32 p1 = (u32)bf16rne(v.z) | ((u32)bf16rne(v.w) << 16);
        int cu = (c4 >> 1) ^ ((tok & 7) << 2);
        *(uint2*)(dst + tok * 128 + cu) = make_uint2(p0, p1);
    }
}

// ---------------------------------------------------------------------------
// prep: pack all MLP weights into MFMA-fragment order as plain bf16 (u16),
// and build WpT = [Whh^T (256 rows) ; Who^T (64 rows)] fp32 for the RNN.
// ---------------------------------------------------------------------------
__global__ __launch_bounds__(256) void prep_kernel(
    const float* __restrict__ Wi1, const float* __restrict__ Wi2,
    const float* __restrict__ Wi3, const float* __restrict__ Wih,
    const float* __restrict__ Wo1, const float* __restrict__ Wo2,
    const float* __restrict__ Wo3,
    const float* __restrict__ Whh, const float* __restrict__ Who,
    u16* __restrict__ Bpk, float* __restrict__ WpT)
{
    int idx = blockIdx.x * 256 + threadIdx.x;
    if (idx < BPK_TOTAL) {
        const float* W; int NF; int i = idx;
        if      (i < OFF_I2) { W = Wi1; NF = 16; i -= OFF_I1; }
        else if (i < OFF_I3) { W = Wi2; NF = 16; i -= OFF_I2; }
        else if (i < OFF_IH) { W = Wi3; NF = 8;  i -= OFF_I3; }
        else if (i < OFF_O1) { W = Wih; NF = 16; i -= OFF_IH; }
        else if (i < OFF_O2) { W = Wo1; NF = 16; i -= OFF_O1; }
        else if (i < OFF_O3) { W = Wo2; NF = 16; i -= OFF_O2; }
        else                 { W = Wo3; NF = 2;  i -= OFF_O3; }
        int e = i & 7, l = (i >> 3) & 63, t = i >> 9;
        int nf = t % NF, kc = t / NF;
        int k = kc * 32 + ((l >> 4) * 8) + e;
        int n = nf * 16 + (l & 15);
        Bpk[idx] = bf16rne(W[(size_t)k * (NF * 16) + n]);
    } else if (idx < BPK_TOTAL + STATE*STATE) {
        int i = idx - BPK_TOTAL; int j = i >> 8, n = i & 255;
        WpT[n * STATE + j] = Whh[j * STATE + n];
    } else if (idx < BPK_TOTAL + STATE*STATE + STATE*MOTOR) {
        int i = idx - BPK_TOTAL - STATE*STATE; int j = i >> 6, o = i & 63;
        WpT[(size_t)(STATE + o) * STATE + j] = Who[j * MOTOR + o];
    }
}

// ---------------------------------------------------------------------------
// MFMA encoder: x -> tanh(Wi1) -> tanh(Wi2) -> Wi3 -> (Wih + bh) = u
// Single 32 KB in-place bf16 buffer, 512 threads, up to 4 blocks/CU.
// ---------------------------------------------------------------------------
__global__ __launch_bounds__(512, 4) void encoder_mfma(
    const float* __restrict__ x, const u16* __restrict__ Bpk,
    const float* __restrict__ bi1, const float* __restrict__ bi2,
    const float* __restrict__ bi3, const float* __restrict__ bh,
    float* __restrict__ u)
{
    __shared__ u32 buf[64 * 128];   // 32 KB bf16 activations
    const int tid = threadIdx.x, lane = tid & 63, wv = tid >> 6;
    const size_t row0 = (size_t)blockIdx.x * 64;

    stage64(x + row0 * DIN, buf, tid);
    __syncthreads();
    mfma_layer<DIN,  H1,    true,  false>(Bpk + OFF_I1, bi1, buf, nullptr, lane, wv);
    mfma_layer<H1,   H1,    true,  false>(Bpk + OFF_I2, bi2, buf, nullptr, lane, wv);
    mfma_layer<H1,   INTER, false, false>(Bpk + OFF_I3, bi3, buf, nullptr, lane, wv);
    mfma_layer<INTER,STATE, false, true >(Bpk + OFF_IH, bh,  buf, u + row0 * STATE, lane, wv);
}

// ---------------------------------------------------------------------------
// MFMA decoder: m -> tanh(Wo1) -> tanh(Wo2) -> Wo3 -> y   (same structure)
// ---------------------------------------------------------------------------
__global__ __launch_bounds__(512, 4) void decoder_mfma(
    const float* __restrict__ m, const u16* __restrict__ Bpk,
    const float* __restrict__ bo1, const float* __restrict__ bo2,
    const float* __restrict__ bo3,
    float* __restrict__ y)
{
    __shared__ u32 buf[64 * 128];   // 32 KB
    const int tid = threadIdx.x, lane = tid & 63, wv = tid >> 6;
    const size_t row0 = (size_t)blockIdx.x * 64;

    stage64(m + row0 * MOTOR, buf, tid);
    __syncthreads();
    mfma_layer<MOTOR, H1,   true,  false>(Bpk + OFF_O1, bo1, buf, nullptr, lane, wv);
    mfma_layer<H1,    H1,   true,  false>(Bpk + OFF_O2, bo2, buf, nullptr, lane, wv);
    mfma_layer<H1,    DOUT, false, true >(Bpk + OFF_O3, bo3, buf, y + row0 * DOUT, lane, wv);
}

// ---------------------------------------------------------------------------
// RNN scan v11 (best measured: 445 us — structural floor, 6 attacks falsified).
// 256 blocks x 1 sample, 512 threads (8 waves, 2/SIMD), 1 barrier/step.
// fp32 weights/state — the recurrence numerics are untouched by v17.
// ---------------------------------------------------------------------------
__global__ __launch_bounds__(512, 2) void rnn_kernel(
    const float* __restrict__ u,      // [B*T, STATE]
    const float* __restrict__ WpT,    // [320][256] = [WhhT ; WhoT]
    const float* __restrict__ bo,     // [MOTOR]
    float* __restrict__ m)            // [B*T, MOTOR]
{
    __shared__ float hb[2][STATE];
    __shared__ float part[64 * 44];   // [g][o][s] : g*44 + o*8 + s

    const int tid   = threadIdx.x;
    const int b     = blockIdx.x;
    const int s     = tid & 7;
    const int g     = tid >> 3;          // 0..63
    const int kbase = s * 32;

    // --- weights -> registers (once), UNIFORM shape/order across threads ---
    float4 wq[5][8];
    #pragma unroll
    for (int o = 0; o < 5; ++o) {
        const int row = (o < 4) ? (4 * g + o) : (STATE + g);
        const float* wr = WpT + (size_t)row * STATE + kbase;
        #pragma unroll
        for (int ii = 0; ii < 8; ++ii)
            wq[o][ii] = *(const float4*)(wr + 4 * ((ii + s) & 7));
    }

    // --- precomputed rotated h-read pointers (both buffers) ---
    const float4* hp0[8];
    const float4* hp1[8];
    #pragma unroll
    for (int ii = 0; ii < 8; ++ii) {
        int off = kbase + 4 * ((ii + s) & 7);
        hp0[ii] = (const float4*)(hb[0] + off);
        hp1[ii] = (const float4*)(hb[1] + off);
    }

    const bool ish  = (s < 4);           // reducer lane for h-row hidx
    const int  hidx = 4 * g + (s & 3);
    const int  pb   = g * 44 + s * 8;    // set base this lane reduces (s<5)

    const float bov  = (s == 4) ? bo[g] : 0.f;
    const float* ubase = u + (size_t)b * TT * STATE + hidx;   // ish lanes
    float*       mst   = m + (size_t)b * TT * MOTOR + g;      // s==4 cursor

    if (tid < STATE) hb[0][tid] = 0.f;
    float up = ish ? ubase[0] : 0.f;   // u_0
    __syncthreads();

#define RNN_BODY(T, HP, HWR)                                                   \
    {                                                                          \
        float upn = 0.f;                                                       \
        if (ish && (T) + 1 < TT) upn = ubase[(size_t)((T) + 1) * STATE];       \
        float a0 = 0.f, a1 = 0.f, a2 = 0.f, a3 = 0.f, a4 = 0.f;                \
        _Pragma("unroll")                                                      \
        for (int ii = 0; ii < 8; ++ii) {                                       \
            float4 hv = *HP[ii];                                               \
            a0 = fmaf(wq[0][ii].x, hv.x, a0); a0 = fmaf(wq[0][ii].y, hv.y, a0);\
            a0 = fmaf(wq[0][ii].z, hv.z, a0); a0 = fmaf(wq[0][ii].w, hv.w, a0);\
            a1 = fmaf(wq[1][ii].x, hv.x, a1); a1 = fmaf(wq[1][ii].y, hv.y, a1);\
            a1 = fmaf(wq[1][ii].z, hv.z, a1); a1 = fmaf(wq[1][ii].w, hv.w, a1);\
            a2 = fmaf(wq[2][ii].x, hv.x, a2); a2 = fmaf(wq[2][ii].y, hv.y, a2);\
            a2 = fmaf(wq[2][ii].z, hv.z, a2); a2 = fmaf(wq[2][ii].w, hv.w, a2);\
            a3 = fmaf(wq[3][ii].x, hv.x, a3); a3 = fmaf(wq[3][ii].y, hv.y, a3);\
            a3 = fmaf(wq[3][ii].z, hv.z, a3); a3 = fmaf(wq[3][ii].w, hv.w, a3);\
            a4 = fmaf(wq[4][ii].x, hv.x, a4); a4 = fmaf(wq[4][ii].y, hv.y, a4);\
            a4 = fmaf(wq[4][ii].z, hv.z, a4); a4 = fmaf(wq[4][ii].w, hv.w, a4);\
        }                                                                      \
        part[g * 44 +  0 + s] = a0;                                            \
        part[g * 44 +  8 + s] = a1;                                            \
        part[g * 44 + 16 + s] = a2;                                            \
        part[g * 44 + 24 + s] = a3;                                            \
        part[g * 44 + 32 + s] = a4;                                            \
        if (s < 5) {                                                           \
            float4 pA = *(const float4*)(part + pb);                           \
            float4 pB = *(const float4*)(part + pb + 4);                       \
            float v = ((pA.x + pA.y) + (pA.z + pA.w))                          \
                    + ((pB.x + pB.y) + (pB.z + pB.w));                         \
            if (ish) {                                                         \
                if ((T) < TT) HWR[hidx] = tanh_fast(v + up);                   \
            } else if ((T) > 0) {                                              \
                mst[0] = v + bov;                                              \
                mst += MOTOR;                                                  \
            }                                                                  \
        }                                                                      \
        __syncthreads();                                                       \
        up = upn;                                                              \
    }

    for (int t = 0; t <= TT; t += 2) {
        RNN_BODY(t,     hp0, (hb[1]));      // even t: read hb0, write hb1
        if (t + 1 <= TT)
            RNN_BODY(t + 1, hp1, (hb[0]));  // odd t: read hb1, write hb0
    }
#undef RNN_BODY
}

// ---------------------------------------------------------------------------
extern "C" void kernel_launch(void* const* d_in, const int* in_sizes, int n_in,
                              void* d_out, int out_size, void* d_ws, size_t ws_size,
                              hipStream_t stream) {
    const float* x   = (const float*)d_in[0];
    const float* Wi1 = (const float*)d_in[1];
    const float* bi1 = (const float*)d_in[2];
    const float* Wi2 = (const float*)d_in[3];
    const float* bi2 = (const float*)d_in[4];
    const float* Wi3 = (const float*)d_in[5];
    const float* bi3 = (const float*)d_in[6];
    const float* Wih = (const float*)d_in[7];
    const float* Whh = (const float*)d_in[8];
    const float* bh  = (const float*)d_in[9];
    const float* Who = (const float*)d_in[10];
    const float* bo  = (const float*)d_in[11];
    const float* Wo1 = (const float*)d_in[12];
    const float* bo1 = (const float*)d_in[13];
    const float* Wo2 = (const float*)d_in[14];
    const float* bo2 = (const float*)d_in[15];
    const float* Wo3 = (const float*)d_in[16];
    const float* bo3 = (const float*)d_in[17];
    float* y = (float*)d_out;

    // workspace (floats): u | mbuf | WpT(320x256) | Bpk(u16)
    float* u    = (float*)d_ws;
    float* mbuf = u    + (size_t)BT * STATE;
    float* WpT  = mbuf + (size_t)BT * MOTOR;
    u16*   Bpk  = (u16*)(WpT + (size_t)(STATE + MOTOR) * STATE);

    int prep_items = BPK_TOTAL + STATE*STATE + STATE*MOTOR;
    prep_kernel<<<(prep_items + 255)/256, 256, 0, stream>>>(
        Wi1, Wi2, Wi3, Wih, Wo1, Wo2, Wo3, Whh, Who, Bpk, WpT);
    encoder_mfma<<<BT/64, 512, 0, stream>>>(x, Bpk, bi1, bi2, bi3, bh, u);
    rnn_kernel<<<BB, 512, 0, stream>>>(u, WpT, bo, mbuf);
    decoder_mfma<<<BT/64, 512, 0, stream>>>(mbuf, Bpk, bo1, bo2, bo3, y);
}